// Round 1
// baseline (360.092 us; speedup 1.0000x reference)
//
#include <hip/hip_runtime.h>
#include <math.h>

// Problem constants (from reference)
#define BB 256      // batch
#define DD 1024     // feat dim
#define AA 1024     // ada dim
#define RR 8        // rank
#define II 1024     // inter dim
#define LN_EPS 1e-5f

__device__ __forceinline__ float gelu_exact(float v) {
    return 0.5f * v * (1.0f + erff(v * 0.70710678118654752f));
}

// ---------------- LayerNorm over ada_dim ----------------
// one block per batch row, 256 threads, each owns 4 contiguous floats
__global__ __launch_bounds__(256) void ln_kernel(const float* __restrict__ ada,
                                                 const float* __restrict__ gamma,
                                                 const float* __restrict__ beta,
                                                 float* __restrict__ cond) {
    const int b = blockIdx.x;
    const int tid = threadIdx.x;
    const float4 v = ((const float4*)(ada + (size_t)b * AA))[tid];

    float s  = v.x + v.y + v.z + v.w;
    float ss = v.x * v.x + v.y * v.y + v.z * v.z + v.w * v.w;
    #pragma unroll
    for (int off = 32; off; off >>= 1) {
        s  += __shfl_down(s, off);
        ss += __shfl_down(ss, off);
    }
    __shared__ float red[2][4];
    const int wid = tid >> 6, lane = tid & 63;
    if (lane == 0) { red[0][wid] = s; red[1][wid] = ss; }
    __syncthreads();
    __shared__ float stats[2];
    if (tid == 0) {
        float S  = red[0][0] + red[0][1] + red[0][2] + red[0][3];
        float SS = red[1][0] + red[1][1] + red[1][2] + red[1][3];
        float mu  = S * (1.0f / AA);
        float var = SS * (1.0f / AA) - mu * mu;
        stats[0] = mu;
        stats[1] = rsqrtf(var + LN_EPS);
    }
    __syncthreads();
    const float mu = stats[0], inv = stats[1];
    const float4 g  = ((const float4*)gamma)[tid];
    const float4 be = ((const float4*)beta)[tid];
    float4 o;
    o.x = (v.x - mu) * inv * g.x + be.x;
    o.y = (v.y - mu) * inv * g.y + be.y;
    o.z = (v.z - mu) * inv * g.z + be.z;
    o.w = (v.w - mu) * inv * g.w + be.w;
    ((float4*)(cond + (size_t)b * AA))[tid] = o;
}

// ---------------- generic tiled fp32 GEMM ----------------
// C[M,N] = A[M,K] @ B[K,N]  (+bias, +gelu per EPI)
// EPI: 0 = none, 1 = bias+gelu, 2 = bias
// 256 threads; thread layout: tx = tid % (BN/TN) over N, ty = tid / (BN/TN) over M
template <int BM, int BN, int BK, int TM, int TN, int EPI>
__global__ __launch_bounds__(256) void gemm_f32(const float* __restrict__ Am,
                                                const float* __restrict__ Bm,
                                                const float* __restrict__ bias,
                                                float* __restrict__ Cm,
                                                int M, int N, int K) {
    __shared__ float As[BK][BM];   // transposed A tile: As[k][m]
    __shared__ float Bs[BK][BN];   // Bs[k][n]

    const int tid = threadIdx.x;
    const int tx = tid % (BN / TN);
    const int ty = tid / (BN / TN);
    const int bn = blockIdx.x * BN;
    const int bm = blockIdx.y * BM;

    float acc[TM][TN];
    #pragma unroll
    for (int i = 0; i < TM; i++)
        #pragma unroll
        for (int j = 0; j < TN; j++) acc[i][j] = 0.0f;

    constexpr int A_IT = (BM * BK / 4) / 256;   // float4 loads per thread (A)
    constexpr int B_IT = (BK * BN / 4) / 256;   // float4 loads per thread (B)

    for (int k0 = 0; k0 < K; k0 += BK) {
        // stage A (transposed) and B
        #pragma unroll
        for (int i = 0; i < A_IT; i++) {
            int slot = tid + i * 256;
            int row  = slot / (BK / 4);
            int kq   = (slot % (BK / 4)) * 4;
            float4 v = *(const float4*)&Am[(size_t)(bm + row) * K + k0 + kq];
            As[kq + 0][row] = v.x;
            As[kq + 1][row] = v.y;
            As[kq + 2][row] = v.z;
            As[kq + 3][row] = v.w;
        }
        #pragma unroll
        for (int i = 0; i < B_IT; i++) {
            int slot = tid + i * 256;
            int krow = slot / (BN / 4);
            int nq   = (slot % (BN / 4)) * 4;
            float4 v = *(const float4*)&Bm[(size_t)(k0 + krow) * N + bn + nq];
            *(float4*)&Bs[krow][nq] = v;
        }
        __syncthreads();

        #pragma unroll
        for (int k = 0; k < BK; k++) {
            float ar[TM], br[TN];
            #pragma unroll
            for (int i = 0; i < TM; i += 4)
                *(float4*)&ar[i] = *(const float4*)&As[k][ty * TM + i];
            #pragma unroll
            for (int j = 0; j < TN; j += 4)
                *(float4*)&br[j] = *(const float4*)&Bs[k][tx * TN + j];
            #pragma unroll
            for (int i = 0; i < TM; i++)
                #pragma unroll
                for (int j = 0; j < TN; j++)
                    acc[i][j] = fmaf(ar[i], br[j], acc[i][j]);
        }
        __syncthreads();
    }

    // epilogue
    #pragma unroll
    for (int i = 0; i < TM; i++) {
        const int row = bm + ty * TM + i;
        #pragma unroll
        for (int j4 = 0; j4 < TN; j4 += 4) {
            const int col = bn + tx * TN + j4;
            float4 o;
            o.x = acc[i][j4 + 0];
            o.y = acc[i][j4 + 1];
            o.z = acc[i][j4 + 2];
            o.w = acc[i][j4 + 3];
            if (EPI >= 1) {
                const float4 bv = *(const float4*)&bias[col];
                o.x += bv.x; o.y += bv.y; o.z += bv.z; o.w += bv.w;
            }
            if (EPI == 1) {
                o.x = gelu_exact(o.x);
                o.y = gelu_exact(o.y);
                o.z = gelu_exact(o.z);
                o.w = gelu_exact(o.w);
            }
            *(float4*)&Cm[(size_t)row * N + col] = o;
        }
    }
}

// ---------------- t[b,r] = sum_c x[b,c] * w[b, c*R + r] ----------------
// one block per batch row; 256 threads, each owns 4 c-values
__global__ __launch_bounds__(256) void t_kernel(const float* __restrict__ x,
                                                const float* __restrict__ w,
                                                float* __restrict__ tmat) {
    const int b = blockIdx.x;
    const int tid = threadIdx.x;
    const float* wa = w + (size_t)b * (2 * DD * RR);       // x_a half
    const float4 xv = ((const float4*)(x + (size_t)b * DD))[tid];
    const float xs[4] = {xv.x, xv.y, xv.z, xv.w};

    float acc[RR] = {};
    #pragma unroll
    for (int i = 0; i < 4; i++) {
        const int c = tid * 4 + i;
        const float4 w0 = *(const float4*)&wa[c * RR];
        const float4 w1 = *(const float4*)&wa[c * RR + 4];
        acc[0] = fmaf(xs[i], w0.x, acc[0]);
        acc[1] = fmaf(xs[i], w0.y, acc[1]);
        acc[2] = fmaf(xs[i], w0.z, acc[2]);
        acc[3] = fmaf(xs[i], w0.w, acc[3]);
        acc[4] = fmaf(xs[i], w1.x, acc[4]);
        acc[5] = fmaf(xs[i], w1.y, acc[5]);
        acc[6] = fmaf(xs[i], w1.z, acc[6]);
        acc[7] = fmaf(xs[i], w1.w, acc[7]);
    }
    __shared__ float red[4][RR];
    const int wid = tid >> 6, lane = tid & 63;
    #pragma unroll
    for (int r = 0; r < RR; r++) {
        float v = acc[r];
        #pragma unroll
        for (int off = 32; off; off >>= 1) v += __shfl_down(v, off);
        if (lane == 0) red[wid][r] = v;
    }
    __syncthreads();
    if (tid < RR) {
        tmat[b * RR + tid] = red[0][tid] + red[1][tid] + red[2][tid] + red[3][tid];
    }
}

// ---------------- out = x + x@base + sum_r t[b,r]*x_b[b,o,r] ----------------
__global__ __launch_bounds__(256) void final_kernel(const float* __restrict__ x,
                                                    const float* __restrict__ y,
                                                    const float* __restrict__ w,
                                                    const float* __restrict__ tmat,
                                                    float* __restrict__ out) {
    const int b = blockIdx.x;
    const int tid = threadIdx.x;
    float tr[RR];
    #pragma unroll
    for (int r = 0; r < RR; r++) tr[r] = tmat[b * RR + r];

    const float* wb = w + (size_t)b * (2 * DD * RR) + DD * RR;  // x_b half
    const int o0 = tid * 4;
    const float4 xv = *(const float4*)&x[(size_t)b * DD + o0];
    const float4 yv = *(const float4*)&y[(size_t)b * DD + o0];

    float vals[4];
    #pragma unroll
    for (int i = 0; i < 4; i++) {
        const float4 w0 = *(const float4*)&wb[(o0 + i) * RR];
        const float4 w1 = *(const float4*)&wb[(o0 + i) * RR + 4];
        vals[i] = tr[0] * w0.x + tr[1] * w0.y + tr[2] * w0.z + tr[3] * w0.w
                + tr[4] * w1.x + tr[5] * w1.y + tr[6] * w1.z + tr[7] * w1.w;
    }
    float4 o;
    o.x = xv.x + yv.x + vals[0];
    o.y = xv.y + yv.y + vals[1];
    o.z = xv.z + yv.z + vals[2];
    o.w = xv.w + yv.w + vals[3];
    *(float4*)&out[(size_t)b * DD + o0] = o;
}

extern "C" void kernel_launch(void* const* d_in, const int* in_sizes, int n_in,
                              void* d_out, int out_size, void* d_ws, size_t ws_size,
                              hipStream_t stream) {
    const float* x     = (const float*)d_in[0];
    const float* ada   = (const float*)d_in[1];
    const float* base  = (const float*)d_in[2];
    const float* gamma = (const float*)d_in[3];
    const float* beta  = (const float*)d_in[4];
    const float* W1    = (const float*)d_in[5];
    const float* b1    = (const float*)d_in[6];
    const float* W2    = (const float*)d_in[7];
    const float* b2    = (const float*)d_in[8];
    float* out = (float*)d_out;

    float* ws   = (float*)d_ws;
    float* cond = ws;                       // B*A      = 262144
    float* h    = cond + (size_t)BB * AA;   // B*I      = 262144
    float* w    = h + (size_t)BB * II;      // B*2*D*R  = 4194304
    float* y    = w + (size_t)BB * 2 * DD * RR; // B*D  = 262144
    float* tmat = y + (size_t)BB * DD;      // B*R      = 2048

    // 1) LayerNorm
    ln_kernel<<<BB, 256, 0, stream>>>(ada, gamma, beta, cond);

    // 2) y = x @ base            [256,1024] @ [1024,1024]
    gemm_f32<64, 64, 16, 4, 4, 0><<<dim3(DD / 64, BB / 64), 256, 0, stream>>>(
        x, base, nullptr, y, BB, DD, DD);

    // 3) h = gelu(cond @ W1 + b1) [256,1024] @ [1024,1024]
    gemm_f32<64, 64, 16, 4, 4, 1><<<dim3(II / 64, BB / 64), 256, 0, stream>>>(
        cond, W1, b1, h, BB, II, AA);

    // 4) w = h @ W2 + b2          [256,1024] @ [1024,16384]  -- dominant GEMM
    gemm_f32<128, 64, 16, 8, 4, 2><<<dim3((2 * DD * RR) / 64, BB / 128), 256, 0, stream>>>(
        h, W2, b2, w, BB, 2 * DD * RR, II);

    // 5) t[b,r] = sum_c x[b,c] * x_a[b,c,r]
    t_kernel<<<BB, 256, 0, stream>>>(x, w, tmat);

    // 6) out = x + y + sum_r t[b,r] * x_b[b,:,r]
    final_kernel<<<BB, 256, 0, stream>>>(x, y, w, tmat, out);
}

// Round 2
// 203.319 us; speedup vs baseline: 1.7711x; 1.7711x over previous
//
#include <hip/hip_runtime.h>
#include <math.h>

// Problem constants (from reference)
#define BB 256      // batch
#define DD 1024     // feat dim
#define AA 1024     // ada dim
#define RR 8        // rank
#define II 1024     // inter dim
#define NOUT (2*DD*RR)  // 16384
#define LN_EPS 1e-5f

typedef __attribute__((ext_vector_type(8))) short bf16x8;   // 8 bf16 = 4 VGPRs
typedef __attribute__((ext_vector_type(4))) float f32x4;    // MFMA 16x16 acc

__device__ __forceinline__ f32x4 mfma16(bf16x8 a, bf16x8 b, f32x4 c) {
    return __builtin_amdgcn_mfma_f32_16x16x32_bf16(a, b, c, 0, 0, 0);
}

// fp32 -> bf16 RNE, bit-level
__device__ __forceinline__ unsigned short f2bf(float x) {
    unsigned int u = __float_as_uint(x);
    unsigned int r = (u + 0x7fffu + ((u >> 16) & 1u)) >> 16;
    return (unsigned short)r;
}
__device__ __forceinline__ float bf2f(unsigned short b) {
    return __uint_as_float(((unsigned int)b) << 16);
}
// split x ~= hi + lo (each bf16): ~17 mantissa bits total
__device__ __forceinline__ void split2(float x, unsigned short& hi, unsigned short& lo) {
    hi = f2bf(x);
    lo = f2bf(x - bf2f(hi));
}

__device__ __forceinline__ float gelu_exact(float v) {
    return 0.5f * v * (1.0f + erff(v * 0.70710678118654752f));
}

// ---------------- LayerNorm over ada_dim (fp32 out) ----------------
__global__ __launch_bounds__(256) void ln_kernel(const float* __restrict__ ada,
                                                 const float* __restrict__ gamma,
                                                 const float* __restrict__ beta,
                                                 float* __restrict__ cond) {
    const int b = blockIdx.x;
    const int tid = threadIdx.x;
    const float4 v = ((const float4*)(ada + (size_t)b * AA))[tid];

    float s  = v.x + v.y + v.z + v.w;
    float ss = v.x * v.x + v.y * v.y + v.z * v.z + v.w * v.w;
    #pragma unroll
    for (int off = 32; off; off >>= 1) {
        s  += __shfl_down(s, off);
        ss += __shfl_down(ss, off);
    }
    __shared__ float red[2][4];
    const int wid = tid >> 6, lane = tid & 63;
    if (lane == 0) { red[0][wid] = s; red[1][wid] = ss; }
    __syncthreads();
    __shared__ float stats[2];
    if (tid == 0) {
        float S  = red[0][0] + red[0][1] + red[0][2] + red[0][3];
        float SS = red[1][0] + red[1][1] + red[1][2] + red[1][3];
        float mu  = S * (1.0f / AA);
        float var = SS * (1.0f / AA) - mu * mu;
        stats[0] = mu;
        stats[1] = rsqrtf(var + LN_EPS);
    }
    __syncthreads();
    const float mu = stats[0], inv = stats[1];
    const float4 g  = ((const float4*)gamma)[tid];
    const float4 be = ((const float4*)beta)[tid];
    float4 o;
    o.x = (v.x - mu) * inv * g.x + be.x;
    o.y = (v.y - mu) * inv * g.y + be.y;
    o.z = (v.z - mu) * inv * g.z + be.z;
    o.w = (v.w - mu) * inv * g.w + be.w;
    ((float4*)(cond + (size_t)b * AA))[tid] = o;
}

// ---------------- fused small GEMMs (split-bf16 MFMA) ----------------
// z=0: y = x @ base                 (fp32 out)
// z=1: h = gelu(cond @ W1 + b1)     (out as bf16 hi/lo planes)
// M=256, N=1024, K=1024. BM=BN=64, BK=32, 256 thr = 4 waves (2x2), wave 32x32.
__global__ __launch_bounds__(256) void gemm_small(const float* __restrict__ x,
                                                  const float* __restrict__ cond,
                                                  const float* __restrict__ base,
                                                  const float* __restrict__ W1,
                                                  const float* __restrict__ b1,
                                                  float* __restrict__ y,
                                                  unsigned short* __restrict__ h_hi,
                                                  unsigned short* __restrict__ h_lo) {
    __shared__ __align__(16) unsigned short As[2][64][40];  // [plane][m][k] pad->40
    __shared__ __align__(16) unsigned short Bs[2][64][40];  // [plane][n][k]

    const int z = blockIdx.z;
    const float* __restrict__ Asrc = z ? cond : x;
    const float* __restrict__ Bsrc = z ? W1 : base;

    const int tid = threadIdx.x;
    const int bn = blockIdx.x * 64;
    const int bm = blockIdx.y * 64;
    const int wid = tid >> 6, l = tid & 63;
    const int wm = wid >> 1, wn = wid & 1;
    const int lrow = l & 15;
    const int lk = (l >> 4) << 3;   // 0,8,16,24

    f32x4 acc[2][2];
    #pragma unroll
    for (int i = 0; i < 2; i++)
        #pragma unroll
        for (int j = 0; j < 2; j++) acc[i][j] = (f32x4)0.0f;

    const int an = tid & 63, akq = (tid >> 6) << 2;  // B-stage coords

    for (int k0 = 0; k0 < 1024; k0 += 32) {
        // stage A (fp32 -> split planes): 2 float4 slots per thread
        #pragma unroll
        for (int i = 0; i < 2; i++) {
            int slot = tid + i * 256;
            int row = slot >> 3, kq = (slot & 7) << 2;
            float4 v = *(const float4*)&Asrc[(size_t)(bm + row) * 1024 + k0 + kq];
            ushort4 H, L;
            split2(v.x, H.x, L.x); split2(v.y, H.y, L.y);
            split2(v.z, H.z, L.z); split2(v.w, H.w, L.w);
            *(ushort4*)&As[0][row][kq] = H;
            *(ushort4*)&As[1][row][kq] = L;
        }
        // stage B: n = tid&63, two k-halves of 4
        #pragma unroll
        for (int h = 0; h < 32; h += 16) {
            float v[4];
            #pragma unroll
            for (int i = 0; i < 4; i++)
                v[i] = Bsrc[(size_t)(k0 + akq + h + i) * 1024 + bn + an];
            ushort4 H, L;
            split2(v[0], H.x, L.x); split2(v[1], H.y, L.y);
            split2(v[2], H.z, L.z); split2(v[3], H.w, L.w);
            *(ushort4*)&Bs[0][an][akq + h] = H;
            *(ushort4*)&Bs[1][an][akq + h] = L;
        }
        __syncthreads();

        bf16x8 a[2][2], bf[2][2];
        #pragma unroll
        for (int pl = 0; pl < 2; pl++) {
            #pragma unroll
            for (int mi = 0; mi < 2; mi++)
                a[pl][mi] = *(const bf16x8*)&As[pl][wm * 32 + mi * 16 + lrow][lk];
            #pragma unroll
            for (int ni = 0; ni < 2; ni++)
                bf[pl][ni] = *(const bf16x8*)&Bs[pl][wn * 32 + ni * 16 + lrow][lk];
        }
        #pragma unroll
        for (int mi = 0; mi < 2; mi++)
            #pragma unroll
            for (int ni = 0; ni < 2; ni++) {
                acc[mi][ni] = mfma16(a[0][mi], bf[0][ni], acc[mi][ni]);  // hi*hi
                acc[mi][ni] = mfma16(a[0][mi], bf[1][ni], acc[mi][ni]);  // hi*lo
                acc[mi][ni] = mfma16(a[1][mi], bf[0][ni], acc[mi][ni]);  // lo*hi
            }
        __syncthreads();
    }

    // epilogue: C row = (l>>4)*4 + j, col = lane&15  [m89-verified]
    #pragma unroll
    for (int mi = 0; mi < 2; mi++) {
        #pragma unroll
        for (int ni = 0; ni < 2; ni++) {
            const int row0 = bm + wm * 32 + mi * 16 + (l >> 4) * 4;
            const int col  = bn + wn * 32 + ni * 16 + lrow;
            #pragma unroll
            for (int j = 0; j < 4; j++) {
                float v = acc[mi][ni][j];
                if (z == 0) {
                    y[(size_t)(row0 + j) * 1024 + col] = v;
                } else {
                    float g = gelu_exact(v + b1[col]);
                    unsigned short hi, lo;
                    split2(g, hi, lo);
                    h_hi[(size_t)(row0 + j) * 1024 + col] = hi;
                    h_lo[(size_t)(row0 + j) * 1024 + col] = lo;
                }
            }
        }
    }
}

// ---------------- big GEMM: w = h @ W2 + b2 (split-bf16 MFMA) ----------------
// M=256 (=BM, whole M so W2 converted exactly once), N=16384, K=1024.
// BN=64, BK=32, 512 thr = 8 waves stacked along M, wave tile 32x64 (FM=2,FN=4).
__global__ __launch_bounds__(512) void gemm_big(const unsigned short* __restrict__ Ahi,
                                                const unsigned short* __restrict__ Alo,
                                                const float* __restrict__ Bm,
                                                const float* __restrict__ bias,
                                                float* __restrict__ Cm) {
    __shared__ __align__(16) unsigned short As[2][256][40];  // 40 KB
    __shared__ __align__(16) unsigned short Bs[2][64][40];   // 10 KB

    const int tid = threadIdx.x;
    const int bn = blockIdx.x * 64;
    const int wid = tid >> 6, l = tid & 63;
    const int lrow = l & 15;
    const int lk = (l >> 4) << 3;

    f32x4 acc[2][4];
    #pragma unroll
    for (int i = 0; i < 2; i++)
        #pragma unroll
        for (int j = 0; j < 4; j++) acc[i][j] = (f32x4)0.0f;

    const int sn = tid & 63, skq = (tid >> 6) << 2;  // B-stage coords

    for (int k0 = 0; k0 < 1024; k0 += 32) {
        // stage A: pre-split h planes, 4 x ushort4 per thread per plane
        #pragma unroll
        for (int i = 0; i < 4; i++) {
            int slot = tid + i * 512;
            int row = slot >> 3, kq = (slot & 7) << 2;
            *(ushort4*)&As[0][row][kq] = *(const ushort4*)&Ahi[(size_t)row * II + k0 + kq];
            *(ushort4*)&As[1][row][kq] = *(const ushort4*)&Alo[(size_t)row * II + k0 + kq];
        }
        // stage B: W2 fp32 -> split; 4 scalar loads (each wave-coalesced 256B)
        {
            float v[4];
            #pragma unroll
            for (int i = 0; i < 4; i++)
                v[i] = Bm[(size_t)(k0 + skq + i) * NOUT + bn + sn];
            ushort4 H, L;
            split2(v[0], H.x, L.x); split2(v[1], H.y, L.y);
            split2(v[2], H.z, L.z); split2(v[3], H.w, L.w);
            *(ushort4*)&Bs[0][sn][skq] = H;
            *(ushort4*)&Bs[1][sn][skq] = L;
        }
        __syncthreads();

        bf16x8 a[2][2], bf[2][4];
        #pragma unroll
        for (int pl = 0; pl < 2; pl++) {
            #pragma unroll
            for (int mi = 0; mi < 2; mi++)
                a[pl][mi] = *(const bf16x8*)&As[pl][wid * 32 + mi * 16 + lrow][lk];
            #pragma unroll
            for (int ni = 0; ni < 4; ni++)
                bf[pl][ni] = *(const bf16x8*)&Bs[pl][ni * 16 + lrow][lk];
        }
        #pragma unroll
        for (int mi = 0; mi < 2; mi++)
            #pragma unroll
            for (int ni = 0; ni < 4; ni++) {
                acc[mi][ni] = mfma16(a[0][mi], bf[0][ni], acc[mi][ni]);  // hi*hi
                acc[mi][ni] = mfma16(a[0][mi], bf[1][ni], acc[mi][ni]);  // hi*lo
                acc[mi][ni] = mfma16(a[1][mi], bf[0][ni], acc[mi][ni]);  // lo*hi
            }
        __syncthreads();
    }

    // epilogue: + bias, fp32 store
    #pragma unroll
    for (int mi = 0; mi < 2; mi++) {
        #pragma unroll
        for (int ni = 0; ni < 4; ni++) {
            const int row0 = wid * 32 + mi * 16 + (l >> 4) * 4;
            const int col  = bn + ni * 16 + lrow;
            const float bv = bias[col];
            #pragma unroll
            for (int j = 0; j < 4; j++)
                Cm[(size_t)(row0 + j) * NOUT + col] = acc[mi][ni][j] + bv;
        }
    }
}

// ---------------- t[b,r] = sum_c x[b,c] * x_a[b,c,r] ----------------
__global__ __launch_bounds__(256) void t_kernel(const float* __restrict__ x,
                                                const float* __restrict__ w,
                                                float* __restrict__ tmat) {
    const int b = blockIdx.x;
    const int tid = threadIdx.x;
    const float* wa = w + (size_t)b * NOUT;  // x_a half
    const float4 xv = ((const float4*)(x + (size_t)b * DD))[tid];
    const float xs[4] = {xv.x, xv.y, xv.z, xv.w};

    float acc[RR] = {};
    #pragma unroll
    for (int i = 0; i < 4; i++) {
        const int c = tid * 4 + i;
        const float4 w0 = *(const float4*)&wa[c * RR];
        const float4 w1 = *(const float4*)&wa[c * RR + 4];
        acc[0] = fmaf(xs[i], w0.x, acc[0]);
        acc[1] = fmaf(xs[i], w0.y, acc[1]);
        acc[2] = fmaf(xs[i], w0.z, acc[2]);
        acc[3] = fmaf(xs[i], w0.w, acc[3]);
        acc[4] = fmaf(xs[i], w1.x, acc[4]);
        acc[5] = fmaf(xs[i], w1.y, acc[5]);
        acc[6] = fmaf(xs[i], w1.z, acc[6]);
        acc[7] = fmaf(xs[i], w1.w, acc[7]);
    }
    __shared__ float red[4][RR];
    const int wid = tid >> 6, lane = tid & 63;
    #pragma unroll
    for (int r = 0; r < RR; r++) {
        float v = acc[r];
        #pragma unroll
        for (int off = 32; off; off >>= 1) v += __shfl_down(v, off);
        if (lane == 0) red[wid][r] = v;
    }
    __syncthreads();
    if (tid < RR) {
        tmat[b * RR + tid] = red[0][tid] + red[1][tid] + red[2][tid] + red[3][tid];
    }
}

// ---------------- out = x + y + sum_r t[b,r]*x_b[b,o,r] ----------------
__global__ __launch_bounds__(256) void final_kernel(const float* __restrict__ x,
                                                    const float* __restrict__ y,
                                                    const float* __restrict__ w,
                                                    const float* __restrict__ tmat,
                                                    float* __restrict__ out) {
    const int b = blockIdx.x;
    const int tid = threadIdx.x;
    float tr[RR];
    #pragma unroll
    for (int r = 0; r < RR; r++) tr[r] = tmat[b * RR + r];

    const float* wb = w + (size_t)b * NOUT + DD * RR;  // x_b half
    const int o0 = tid * 4;
    const float4 xv = *(const float4*)&x[(size_t)b * DD + o0];
    const float4 yv = *(const float4*)&y[(size_t)b * DD + o0];

    float vals[4];
    #pragma unroll
    for (int i = 0; i < 4; i++) {
        const float4 w0 = *(const float4*)&wb[(o0 + i) * RR];
        const float4 w1 = *(const float4*)&wb[(o0 + i) * RR + 4];
        vals[i] = tr[0] * w0.x + tr[1] * w0.y + tr[2] * w0.z + tr[3] * w0.w
                + tr[4] * w1.x + tr[5] * w1.y + tr[6] * w1.z + tr[7] * w1.w;
    }
    float4 o;
    o.x = xv.x + yv.x + vals[0];
    o.y = xv.y + yv.y + vals[1];
    o.z = xv.z + yv.z + vals[2];
    o.w = xv.w + yv.w + vals[3];
    *(float4*)&out[(size_t)b * DD + o0] = o;
}

extern "C" void kernel_launch(void* const* d_in, const int* in_sizes, int n_in,
                              void* d_out, int out_size, void* d_ws, size_t ws_size,
                              hipStream_t stream) {
    const float* x     = (const float*)d_in[0];
    const float* ada   = (const float*)d_in[1];
    const float* base  = (const float*)d_in[2];
    const float* gamma = (const float*)d_in[3];
    const float* beta  = (const float*)d_in[4];
    const float* W1    = (const float*)d_in[5];
    const float* b1    = (const float*)d_in[6];
    const float* W2    = (const float*)d_in[7];
    const float* b2    = (const float*)d_in[8];
    float* out = (float*)d_out;

    // ws layout (total 19,931,136 B == round-1 footprint, proven available)
    char* wsb = (char*)d_ws;
    float* w    = (float*)(wsb);                         // 16,777,216 B
    float* y    = (float*)(wsb + 16777216);              //  1,048,576 B
    float* cond = (float*)(wsb + 17825792);              //  1,048,576 B
    unsigned short* h_hi = (unsigned short*)(wsb + 18874368);  // 524,288 B
    unsigned short* h_lo = (unsigned short*)(wsb + 19398656);  // 524,288 B
    float* tmat = (float*)(wsb + 19922944);              //      8,192 B

    // 1) LayerNorm -> cond (fp32)
    ln_kernel<<<BB, 256, 0, stream>>>(ada, gamma, beta, cond);

    // 2) fused: z=0 y = x@base ; z=1 h = gelu(cond@W1+b1) -> split planes
    gemm_small<<<dim3(DD / 64, BB / 64, 2), 256, 0, stream>>>(
        x, cond, base, W1, b1, y, h_hi, h_lo);

    // 3) w = h @ W2 + b2  (dominant GEMM, split-bf16 MFMA)
    gemm_big<<<dim3(NOUT / 64, 1), 512, 0, stream>>>(h_hi, h_lo, W2, b2, w);

    // 4) t[b,r] = sum_c x[b,c] * x_a[b,c,r]
    t_kernel<<<BB, 256, 0, stream>>>(x, w, tmat);

    // 5) out = x + y + sum_r t[b,r] * x_b[b,:,r]
    final_kernel<<<BB, 256, 0, stream>>>(x, y, w, tmat, out);
}